// Round 1
// baseline (1268.244 us; speedup 1.0000x reference)
//
#include <hip/hip_runtime.h>
#include <hip/hip_bf16.h>
#include <math.h>
#include <float.h>

#define T_LEN 1024
#define KNL 1024      // know_length K
#define H_DIM 256
#define E_DIM 64
#define TOPICN 100
#define EXLEN 768
#define KH (KNL*H_DIM) // 262144
#define TOPK 64

// ws offsets (in floats)
#define WS_V     0      // 100
#define WS_KN    128    // 64
#define WS_BA    256    // 1024
#define WS_IDX   1280   // 64 ints
#define WS_BETA  1344   // 64
#define WS_ALPHA 1408   // 1024
#define WS_Y     2432   // 768
#define WS_PP    3200   // 64*256 = 16384  (ends at 19584 floats ~ 78 KB)

typedef __attribute__((ext_vector_type(8))) short short8;
typedef __attribute__((ext_vector_type(4))) float floatx4;

__device__ __forceinline__ float wave_reduce_sum(float v){
  #pragma unroll
  for (int s = 32; s; s >>= 1) v += __shfl_down(v, s);
  return v;  // total in lane 0
}

__device__ __forceinline__ short f2bf(float f){
  unsigned u = __builtin_bit_cast(unsigned, f);
  u = u + 0x7fffu + ((u >> 16) & 1u);   // RNE
  return (short)(u >> 16);
}

// K1: v = W_resize@ex_e + b_resize  (blocks 0..99, one wave per row)
//     kn = Wk@co_e + bk             (blocks 100..163)
__global__ void k1_v_kn(const float* __restrict__ Wr, const float* __restrict__ br,
                        const float* __restrict__ ex, const float* __restrict__ Wk,
                        const float* __restrict__ bk, const float* __restrict__ co,
                        float* __restrict__ wsf){
  int b = blockIdx.x, l = threadIdx.x;
  if (b < TOPICN){
    const float* row = Wr + b*EXLEN;
    float s = 0.f;
    #pragma unroll
    for (int i = 0; i < EXLEN/64; i++) s += row[l + 64*i]*ex[l + 64*i];
    s = wave_reduce_sum(s);
    if (l == 0) wsf[WS_V + b] = s + br[b];
  } else {
    int r = b - TOPICN;
    const float* row = Wk + r*KNL;
    float s = 0.f;
    #pragma unroll
    for (int i = 0; i < KNL/64; i++) s += row[l + 64*i]*co[l + 64*i];
    s = wave_reduce_sum(s);
    if (l == 0) wsf[WS_KN + r] = s + bk[r];
  }
}

// K2: beta_all[t] = vs[t,:] @ v
__global__ void k2_beta_all(const float* __restrict__ vs, float* __restrict__ wsf){
  __shared__ float vl[TOPICN];
  int t = threadIdx.x;
  if (t < TOPICN) vl[t] = wsf[WS_V + t];
  __syncthreads();
  int row = blockIdx.x*256 + t;
  const float* r = vs + row*TOPICN;
  float acc = 0.f;
  #pragma unroll 10
  for (int i = 0; i < TOPICN; i++) acc += r[i]*vl[i];
  wsf[WS_BA + row] = acc;
}

// K3: top-64 of beta_all + softmax -> idx[64], beta[64]. Single wave.
__global__ void k3_topk(float* __restrict__ wsf){
  int l = threadIdx.x;
  const float* ba = wsf + WS_BA;
  float bv[16];
  #pragma unroll
  for (int i = 0; i < 16; i++) bv[i] = ba[l*16 + i];

  float lm; int la;
  {
    lm = bv[0]; la = l*16;
    #pragma unroll
    for (int i = 1; i < 16; i++) if (bv[i] > lm){ lm = bv[i]; la = l*16 + i; }
  }
  __shared__ float topv[64];
  __shared__ int   topi[64];
  for (int it = 0; it < 64; it++){
    float m = lm; int a = la;
    #pragma unroll
    for (int s = 32; s; s >>= 1){
      float om = __shfl_down(m, s);
      int   oa = __shfl_down(a, s);
      if (om > m){ m = om; a = oa; }
    }
    int widx = __shfl(a, 0);
    float wv = __shfl(m, 0);
    if (l == 0){ topv[it] = wv; topi[it] = widx; }
    if (l == (widx >> 4)){
      bv[widx & 15] = -FLT_MAX;
      lm = bv[0]; la = l*16;
      #pragma unroll
      for (int i = 1; i < 16; i++) if (bv[i] > lm){ lm = bv[i]; la = l*16 + i; }
    }
  }
  __syncthreads();
  float mx = topv[0];                    // descending -> first is max
  float e = expf(topv[l] - mx);
  float ssum = wave_reduce_sum(e);
  ssum = __shfl(ssum, 0);
  wsf[WS_BETA + l] = e/ssum;
  ((int*)wsf)[WS_IDX + l] = topi[l];
}

// K4: alpha = softmax(km @ kn), one block of 1024
__global__ void k4_alpha(const float* __restrict__ km, float* __restrict__ wsf){
  __shared__ float red[1024];
  __shared__ float knl_s[E_DIM];
  int t = threadIdx.x;
  if (t < E_DIM) knl_s[t] = wsf[WS_KN + t];
  __syncthreads();
  const float* row = km + t*E_DIM;
  float m = 0.f;
  #pragma unroll 16
  for (int i = 0; i < E_DIM; i++) m += row[i]*knl_s[i];
  red[t] = m; __syncthreads();
  for (int s = 512; s; s >>= 1){ if (t < s) red[t] = fmaxf(red[t], red[t+s]); __syncthreads(); }
  float M = red[0]; __syncthreads();
  float e = expf(m - M);
  red[t] = e; __syncthreads();
  for (int s = 512; s; s >>= 1){ if (t < s) red[t] += red[t+s]; __syncthreads(); }
  wsf[WS_ALPHA + t] = e / red[0];
}

// K5: partial[bid][h] = beta_j * sum_{k in chunk} alpha_k * hs[idx_j, k, h]
// grid 1024 = 64 j * 16 k-chunks; partials land in d_out+1 (1024x256 floats)
__global__ void k5_partial(const float* __restrict__ hs, const float* __restrict__ wsf,
                           float* __restrict__ P){
  int bid = blockIdx.x;
  int j = bid & 63, kc = bid >> 6;
  int t = threadIdx.x;
  int rowi = ((const int*)wsf)[WS_IDX + j];
  float bj = wsf[WS_BETA + j];
  const float* alpha = wsf + WS_ALPHA + kc*64;
  const float* base = hs + (size_t)rowi*KH + (size_t)(kc*64)*H_DIM + t;
  float acc = 0.f;
  #pragma unroll 16
  for (int i = 0; i < 64; i++) acc += alpha[i]*base[(size_t)i*H_DIM];
  P[bid*256 + t] = bj*acc;
}

// K6a: first-stage reduce of 1024 partial rows -> 64 rows
__global__ void k6a_red(const float* __restrict__ P, float* __restrict__ wsf){
  int g = blockIdx.x, t = threadIdx.x;
  float acc = 0.f;
  #pragma unroll
  for (int r = 0; r < 16; r++) acc += P[(g*16 + r)*256 + t];
  wsf[WS_PP + g*256 + t] = acc;
}

// K6b: hkp[t] = sum_g pp[g][t]; score = W_score@[v;hkp] + b
__global__ void k6b_score(const float* __restrict__ Wsc, const float* __restrict__ bsc,
                          const float* __restrict__ wsf, float* __restrict__ out){
  __shared__ float red[256];
  int t = threadIdx.x;
  float acc = 0.f;
  #pragma unroll 16
  for (int g = 0; g < 64; g++) acc += wsf[WS_PP + g*256 + t];
  float local = Wsc[TOPICN + t]*acc;
  if (t < TOPICN) local += Wsc[t]*wsf[WS_V + t];
  red[t] = local; __syncthreads();
  for (int s = 128; s; s >>= 1){ if (t < s) red[t] += red[t+s]; __syncthreads(); }
  if (t == 0) out[0] = red[0] + bsc[0];
}

// K7: y = W_ih @ x, x = [v*mask, v*(1-mask), s]
__global__ void k7_y(const float* __restrict__ Wih, const float* __restrict__ sptr,
                     float* __restrict__ wsf){
  __shared__ float xl[201];
  int t = threadIdx.x;
  float s0 = sptr[0];
  float mk = (s0 >= 0.5f) ? 1.f : 0.f;
  if (t < TOPICN) xl[t] = wsf[WS_V + t]*mk;
  else if (t < 200) xl[t] = wsf[WS_V + t - 100]*(1.f - mk);
  else if (t == 200) xl[t] = s0;
  __syncthreads();
  int j = blockIdx.x*256 + t;
  const float* row = Wih + j*201;
  float acc = 0.f;
  #pragma unroll 8
  for (int i = 0; i < 201; i++) acc += row[i]*xl[i];
  wsf[WS_Y + j] = acc;
}

// K8: gh = h0 @ W_hh^T via bf16 MFMA 16x16x32, fused GRU gate epilogue.
// grid 256 = 64 k-blocks(16 rows) x 4 h-blocks(64 cols); 4 waves, wave = h-subtile q.
__global__ __launch_bounds__(256) void k8_gru(
    const float* __restrict__ h0, const float* __restrict__ Whh,
    const float* __restrict__ bih, const float* __restrict__ bhh,
    const float* __restrict__ wsf, float* __restrict__ out){
  __shared__ short Asm[16*72];    // 16 k-rows x 64 c (bf16), row stride 72
  __shared__ short Bsm[192*72];   // 192 j-rows (3 slices x 64 h) x 64 c

  int tid = threadIdx.x;
  int kb = blockIdx.x >> 2;   // 0..63
  int hb = blockIdx.x & 3;    // 0..3
  int k0 = kb*16;
  int hbase = hb*64;
  int w = tid >> 6;           // wave id = q subtile
  int l = tid & 63;

  floatx4 acc0 = {0.f,0.f,0.f,0.f}, acc1 = {0.f,0.f,0.f,0.f}, acc2 = {0.f,0.f,0.f,0.f};

  for (int cc = 0; cc < 4; cc++){
    { // stage A: 16 rows x 64 c -> 256 float4, one per thread
      int r_ = tid >> 4, c4 = tid & 15;
      float4 vv = *((const float4*)(h0 + (size_t)(k0 + r_)*H_DIM + cc*64) + c4);
      short* dst = &Asm[r_*72 + c4*4];
      dst[0] = f2bf(vv.x); dst[1] = f2bf(vv.y); dst[2] = f2bf(vv.z); dst[3] = f2bf(vv.w);
    }
    // stage B: 192 rows x 16 float4 = 3072 float4, 12 per thread
    #pragma unroll
    for (int i = 0; i < 12; i++){
      int idx = tid + 256*i;
      int r_ = idx >> 4, c4 = idx & 15;
      int s_ = r_ >> 6, hl = r_ & 63;
      float4 vv = *((const float4*)(Whh + (size_t)(s_*H_DIM + hbase + hl)*H_DIM + cc*64) + c4);
      short* dst = &Bsm[r_*72 + c4*4];
      dst[0] = f2bf(vv.x); dst[1] = f2bf(vv.y); dst[2] = f2bf(vv.z); dst[3] = f2bf(vv.w);
    }
    __syncthreads();
    int m_ = l & 15, kq = l >> 4;
    #pragma unroll
    for (int kk = 0; kk < 2; kk++){
      short8 a  = *(const short8*)&Asm[m_*72 + kk*32 + kq*8];
      short8 b0 = *(const short8*)&Bsm[(0*64 + w*16 + m_)*72 + kk*32 + kq*8];
      short8 b1 = *(const short8*)&Bsm[(1*64 + w*16 + m_)*72 + kk*32 + kq*8];
      short8 b2 = *(const short8*)&Bsm[(2*64 + w*16 + m_)*72 + kk*32 + kq*8];
      acc0 = __builtin_amdgcn_mfma_f32_16x16x32_bf16(a, b0, acc0, 0, 0, 0);
      acc1 = __builtin_amdgcn_mfma_f32_16x16x32_bf16(a, b1, acc1, 0, 0, 0);
      acc2 = __builtin_amdgcn_mfma_f32_16x16x32_bf16(a, b2, acc2, 0, 0, 0);
    }
    __syncthreads();
  }

  // epilogue: C/D layout col=lane&15, row=(lane>>4)*4+reg  [m89/m91]
  int col = l & 15, kq = l >> 4;
  int h = hbase + w*16 + col;
  const float* y = wsf + WS_Y;
  const float* alpha = wsf + WS_ALPHA;
  float yr = y[h],        yz = y[H_DIM + h],   yn = y[2*H_DIM + h];
  float br_ = bih[h],     bz_ = bih[H_DIM+h],  bn_ = bih[2*H_DIM+h];
  float cr_ = bhh[h],     cz_ = bhh[H_DIM+h],  cn_ = bhh[2*H_DIM+h];
  #pragma unroll
  for (int r_ = 0; r_ < 4; r_++){
    int k = k0 + kq*4 + r_;
    float al = alpha[k];
    float ghr = acc0[r_] + cr_;
    float ghz = acc1[r_] + cz_;
    float ghn = acc2[r_] + cn_;
    float rr = 1.f/(1.f + expf(-(al*yr + br_ + ghr)));
    float zz = 1.f/(1.f + expf(-(al*yz + bz_ + ghz)));
    float nn = tanhf(al*yn + bn_ + rr*ghn);
    float h0v = h0[(size_t)k*H_DIM + h];
    out[1 + (size_t)k*H_DIM + h] = (1.f - zz)*nn + zz*h0v;
  }
}

extern "C" void kernel_launch(void* const* d_in, const int* in_sizes, int n_in,
                              void* d_out, int out_size, void* d_ws, size_t ws_size,
                              hipStream_t stream){
  (void)in_sizes; (void)n_in; (void)out_size; (void)ws_size;
  const float* co_e = (const float*)d_in[0];
  const float* ex_e = (const float*)d_in[1];
  const float* s    = (const float*)d_in[2];
  const float* h0   = (const float*)d_in[3];
  const float* vs   = (const float*)d_in[4];
  const float* hs   = (const float*)d_in[5];
  const float* Wr   = (const float*)d_in[6];
  const float* br   = (const float*)d_in[7];
  const float* Wk   = (const float*)d_in[8];
  const float* bk   = (const float*)d_in[9];
  const float* km   = (const float*)d_in[10];
  const float* Wsc  = (const float*)d_in[11];
  const float* bsc  = (const float*)d_in[12];
  const float* Wih  = (const float*)d_in[13];
  const float* Whh  = (const float*)d_in[14];
  const float* bih  = (const float*)d_in[15];
  const float* bhh  = (const float*)d_in[16];
  float* out = (float*)d_out;
  float* wsf = (float*)d_ws;

  hipLaunchKernelGGL(k1_v_kn,    dim3(164),  dim3(64),   0, stream, Wr, br, ex_e, Wk, bk, co_e, wsf);
  hipLaunchKernelGGL(k2_beta_all,dim3(4),    dim3(256),  0, stream, vs, wsf);
  hipLaunchKernelGGL(k3_topk,    dim3(1),    dim3(64),   0, stream, wsf);
  hipLaunchKernelGGL(k4_alpha,   dim3(1),    dim3(1024), 0, stream, km, wsf);
  hipLaunchKernelGGL(k5_partial, dim3(1024), dim3(256),  0, stream, hs, wsf, out + 1);
  hipLaunchKernelGGL(k6a_red,    dim3(64),   dim3(256),  0, stream, out + 1, wsf);
  hipLaunchKernelGGL(k6b_score,  dim3(1),    dim3(256),  0, stream, Wsc, bsc, wsf, out);
  hipLaunchKernelGGL(k7_y,       dim3(3),    dim3(256),  0, stream, Wih, s, wsf);
  hipLaunchKernelGGL(k8_gru,     dim3(256),  dim3(256),  0, stream, h0, Whh, bih, bhh, wsf, out);
}